// Round 6
// baseline (64.964 us; speedup 1.0000x reference)
//
#include <hip/hip_runtime.h>

#define N_NODES 50000
#define N_EDGES 800000
#define D_IN 256
#define D_OUT 64
#define NEG_SLOPE 0.2f

typedef __attribute__((ext_vector_type(8))) short bf16x8;   // 8 bf16 = 4 VGPR
typedef __attribute__((ext_vector_type(4))) float f32x4;    // MFMA C/D + NT I/O
typedef __attribute__((ext_vector_type(4))) ushort u16x4;   // 8B gather chunk

__device__ inline ushort f2bf(float f) {  // f32 -> bf16 bits, round-nearest-even
  union { float f; unsigned u; } v; v.f = f;
  unsigned r = v.u + 0x7FFFu + ((v.u >> 16) & 1u);
  return (ushort)(r >> 16);
}
__device__ inline float bf2f(ushort h) {
  union { unsigned u; float f; } v; v.u = ((unsigned)h) << 16;
  return v.f;
}

// ---------------------------------------------------------------------------
// Prep (fused): W f32->bf16 (first 16384 threads) + CSR row_ptr from sorted
// edge_dst. NT loads: edge_dst is stream-once.
// ---------------------------------------------------------------------------
__global__ __launch_bounds__(256) void prep_kernel(
    const float* __restrict__ W, ushort* __restrict__ Wb,
    const int* __restrict__ edge_dst, int* __restrict__ row_ptr) {
  const int i = blockIdx.x * 256 + threadIdx.x;
  if (i < D_OUT * D_IN) Wb[i] = f2bf(W[i]);

  const int e = i;
  if (e >= N_EDGES) return;
  const int d = __builtin_nontemporal_load(edge_dst + e);
  if (e == 0) {
    for (int n = 0; n <= d; ++n) row_ptr[n] = 0;
  } else {
    const int dprev = __builtin_nontemporal_load(edge_dst + e - 1);
    if (d != dprev)
      for (int n = dprev + 1; n <= d; ++n) row_ptr[n] = e;
  }
  if (e == N_EDGES - 1)
    for (int n = d + 1; n <= N_NODES; ++n) row_ptr[n] = N_EDGES;
}

// ---------------------------------------------------------------------------
// MFMA GEMM: support[n][o] = sum_k x[n][k]*W[o][k] + b[o], stored as bf16.
// One wave = 16x64 tile, 4 n-blocks x 8 k-steps of mfma_f32_16x16x32_bf16.
// A straight from global x (f32->bf16 in-register, NT: x is stream-once);
// B from bf16 Wb (32 KB, L1-hot). Same lane->k mapping on both operands so
// the internal k-permutation cancels. C/D: col=lane&15, row=(lane>>4)*4+reg.
// ---------------------------------------------------------------------------
__global__ __launch_bounds__(256, 8) void gemm_mfma(
    const float* __restrict__ x, const ushort* __restrict__ Wb,
    const float* __restrict__ bias, ushort* __restrict__ support) {
  const int wave = threadIdx.x >> 6;
  const int lane = threadIdx.x & 63;
  const int m0 = blockIdx.x * 64 + wave * 16;   // this wave's 16 rows
  const int r16 = lane & 15;
  const int kg  = lane >> 4;                    // k-group 0..3

  int arow = m0 + r16;
  if (arow >= N_NODES) arow = N_NODES - 1;      // clamp (dup loads, stores guarded)
  const float*  xp = x  + (size_t)arow * D_IN + kg * 8;
  const ushort* wp = Wb + r16 * D_IN + kg * 8;

  f32x4 acc[4] = {f32x4{0.f,0.f,0.f,0.f}, f32x4{0.f,0.f,0.f,0.f},
                  f32x4{0.f,0.f,0.f,0.f}, f32x4{0.f,0.f,0.f,0.f}};

#pragma unroll
  for (int ks = 0; ks < D_IN / 32; ++ks) {
    const f32x4 xa = __builtin_nontemporal_load(
        reinterpret_cast<const f32x4*>(xp + ks * 32));
    const f32x4 xb = __builtin_nontemporal_load(
        reinterpret_cast<const f32x4*>(xp + ks * 32 + 4));
    bf16x8 a;
    a[0] = (short)f2bf(xa[0]); a[1] = (short)f2bf(xa[1]);
    a[2] = (short)f2bf(xa[2]); a[3] = (short)f2bf(xa[3]);
    a[4] = (short)f2bf(xb[0]); a[5] = (short)f2bf(xb[1]);
    a[6] = (short)f2bf(xb[2]); a[7] = (short)f2bf(xb[3]);
#pragma unroll
    for (int nb = 0; nb < 4; ++nb) {
      const bf16x8 bfrag =
          *reinterpret_cast<const bf16x8*>(wp + nb * 16 * D_IN + ks * 32);
      acc[nb] = __builtin_amdgcn_mfma_f32_16x16x32_bf16(a, bfrag, acc[nb], 0, 0, 0);
    }
  }

#pragma unroll
  for (int nb = 0; nb < 4; ++nb) {
    const int col = nb * 16 + r16;
    const float bv = bias[col];
#pragma unroll
    for (int i = 0; i < 4; ++i) {
      const int row = m0 + kg * 4 + i;          // C/D: row=(lane>>4)*4+reg
      if (row < N_NODES)
        support[(size_t)row * D_OUT + col] = f2bf(acc[nb][i] + bv);
    }
  }
}

// ---------------------------------------------------------------------------
// Aggregation + LeakyReLU, 4 edges per gather instruction.
// One wave per node. Lane = (edge-group eg=lane>>4, col-group cl=lane&15).
// A support row is 64 bf16 = 128 B = 16 lanes x u16x4 (8 B/lane), so one
// gather instruction fetches FOUR edges' full rows: 200K gather insts instead
// of 800K, and 16 edges in flight per wave (4 gathers/iter x 4 edges).
// Tail is branchless: clamped index + cndmask'd val=0. Epilogue: shfl_xor
// (16,32) reduce across edge-groups, 16 lanes store one f32x4 each.
// NT loads for the edge streams; NT store for out (never re-read).
// ---------------------------------------------------------------------------
__global__ __launch_bounds__(256, 8) void agg_kernel(
    const ushort* __restrict__ support, const int* __restrict__ edge_src,
    const float* __restrict__ edge_val, const int* __restrict__ row_ptr,
    float* __restrict__ out) {
  const int wid = (blockIdx.x * 256 + threadIdx.x) >> 6;
  const int lane = threadIdx.x & 63;
  if (wid >= N_NODES) return;
  const int lo = row_ptr[wid];       // wave-uniform -> s_load
  const int hi = row_ptr[wid + 1];
  const int eg = lane >> 4;          // edge group 0..3
  const int cl = lane & 15;          // columns 4*cl .. 4*cl+3

  f32x4 acc0 = {0.f, 0.f, 0.f, 0.f};
  f32x4 acc1 = {0.f, 0.f, 0.f, 0.f};

  for (int e = lo; e < hi; e += 16) {
    int   s[4];
    float v[4];
#pragma unroll
    for (int q = 0; q < 4; ++q) {
      const int idx = e + q * 4 + eg;
      const int ic = idx < hi ? idx : hi - 1;           // clamped (hi>lo here)
      s[q] = __builtin_nontemporal_load(edge_src + ic);
      const float vv = __builtin_nontemporal_load(edge_val + ic);
      v[q] = idx < hi ? vv : 0.f;
    }
#pragma unroll
    for (int q = 0; q < 4; ++q) {
      const u16x4 g = *reinterpret_cast<const u16x4*>(
          support + (size_t)s[q] * D_OUT + cl * 4);
      f32x4& acc = (q & 1) ? acc1 : acc0;
      acc[0] = fmaf(v[q], bf2f(g[0]), acc[0]);
      acc[1] = fmaf(v[q], bf2f(g[1]), acc[1]);
      acc[2] = fmaf(v[q], bf2f(g[2]), acc[2]);
      acc[3] = fmaf(v[q], bf2f(g[3]), acc[3]);
    }
  }

  float r[4] = {acc0[0] + acc1[0], acc0[1] + acc1[1],
                acc0[2] + acc1[2], acc0[3] + acc1[3]};
#pragma unroll
  for (int c = 0; c < 4; ++c) {
    r[c] += __shfl_xor(r[c], 16, 64);   // combine edge groups 0<->1, 2<->3
    r[c] += __shfl_xor(r[c], 32, 64);   // combine {0,1}<->{2,3}
    r[c] = r[c] >= 0.f ? r[c] : NEG_SLOPE * r[c];
  }
  if (eg == 0) {
    f32x4 o = {r[0], r[1], r[2], r[3]};
    __builtin_nontemporal_store(
        o, reinterpret_cast<f32x4*>(out + (size_t)wid * D_OUT + cl * 4));
  }
}

// ---------------------------------------------------------------------------
extern "C" void kernel_launch(void* const* d_in, const int* in_sizes, int n_in,
                              void* d_out, int out_size, void* d_ws, size_t ws_size,
                              hipStream_t stream) {
  const float* x        = (const float*)d_in[0];
  const float* W        = (const float*)d_in[1];
  const float* b        = (const float*)d_in[2];
  const int*   edge_src = (const int*)d_in[3];
  const int*   edge_dst = (const int*)d_in[4];
  const float* edge_val = (const float*)d_in[5];
  float* out = (float*)d_out;

  // workspace layout
  ushort* support = (ushort*)d_ws;                                  // 6.4 MB
  char* p = (char*)d_ws + (size_t)N_NODES * D_OUT * sizeof(ushort);
  int* row_ptr = (int*)p;                                           // 200 KB
  p += (size_t)(N_NODES + 1) * sizeof(int);
  p = (char*)(((uintptr_t)p + 15) & ~(uintptr_t)15);
  ushort* Wb = (ushort*)p;                                          // 32 KB

  hipLaunchKernelGGL(prep_kernel, dim3((N_EDGES + 255) / 256), dim3(256), 0,
                     stream, W, Wb, edge_dst, row_ptr);
  hipLaunchKernelGGL(gemm_mfma, dim3((N_NODES + 63) / 64), dim3(256), 0,
                     stream, x, Wb, b, support);
  hipLaunchKernelGGL(agg_kernel, dim3((N_NODES * 64 + 255) / 256), dim3(256), 0,
                     stream, support, edge_src, edge_val, row_ptr, out);
}

// Round 8
// 64.567 us; speedup vs baseline: 1.0061x; 1.0061x over previous
//
#include <hip/hip_runtime.h>

#define N_NODES 50000
#define N_EDGES 800000
#define D_IN 256
#define D_OUT 64
#define NEG_SLOPE 0.2f

typedef __attribute__((ext_vector_type(8))) short bf16x8;   // 8 bf16 = 4 VGPR
typedef __attribute__((ext_vector_type(4))) float f32x4;    // MFMA C/D + NT I/O
typedef __attribute__((ext_vector_type(4))) ushort u16x4;   // 8B gather chunk

__device__ inline ushort f2bf(float f) {  // f32 -> bf16 bits, round-nearest-even
  union { float f; unsigned u; } v; v.f = f;
  unsigned r = v.u + 0x7FFFu + ((v.u >> 16) & 1u);
  return (ushort)(r >> 16);
}
__device__ inline float bf2f(ushort h) {
  union { unsigned u; float f; } v; v.u = ((unsigned)h) << 16;
  return v.f;
}

// ---------------------------------------------------------------------------
// Prep (fused): W f32->bf16 (first 16384 threads) + CSR row_ptr from sorted
// edge_dst.
// ---------------------------------------------------------------------------
__global__ __launch_bounds__(256) void prep_kernel(
    const float* __restrict__ W, ushort* __restrict__ Wb,
    const int* __restrict__ edge_dst, int* __restrict__ row_ptr) {
  const int i = blockIdx.x * 256 + threadIdx.x;
  if (i < D_OUT * D_IN) Wb[i] = f2bf(W[i]);

  const int e = i;
  if (e >= N_EDGES) return;
  const int d = __builtin_nontemporal_load(edge_dst + e);
  if (e == 0) {
    for (int n = 0; n <= d; ++n) row_ptr[n] = 0;
  } else {
    const int dprev = __builtin_nontemporal_load(edge_dst + e - 1);
    if (d != dprev)
      for (int n = dprev + 1; n <= d; ++n) row_ptr[n] = e;
  }
  if (e == N_EDGES - 1)
    for (int n = d + 1; n <= N_NODES; ++n) row_ptr[n] = N_EDGES;
}

// ---------------------------------------------------------------------------
// MFMA GEMM: support[n][o] = sum_k x[n][k]*W[o][k] + b[o], stored bf16.
// One wave = 16x64 tile. KEY CHANGE vs R4/R6: the wave's whole A-slice
// (16 x f32x4 = 256B/lane, 64 VGPR) is NT-loaded up-front -> 16 loads in
// flight instead of 2; the k-loop then runs convert+MFMA against completed
// data. (256,4): 128-VGPR cap fits the ~100-VGPR live set; grid (782 blocks,
// ~12 waves/CU) was the occupancy limiter anyway, not VGPRs.
// Same lane->k mapping on A and B so the k-permutation cancels.
// C/D: col=lane&15, row=(lane>>4)*4+reg (m89-verified).
// ---------------------------------------------------------------------------
__global__ __launch_bounds__(256, 4) void gemm_mfma(
    const float* __restrict__ x, const ushort* __restrict__ Wb,
    const float* __restrict__ bias, ushort* __restrict__ support) {
  const int wave = threadIdx.x >> 6;
  const int lane = threadIdx.x & 63;
  const int m0 = blockIdx.x * 64 + wave * 16;   // this wave's 16 rows
  const int r16 = lane & 15;
  const int kg  = lane >> 4;                    // k-group 0..3

  int arow = m0 + r16;
  if (arow >= N_NODES) arow = N_NODES - 1;      // clamp (dup loads, stores guarded)
  const float*  xp = x  + (size_t)arow * D_IN + kg * 8;
  const ushort* wp = Wb + r16 * D_IN + kg * 8;

  // Deep preload: issue all 16 A-loads before any consumer.
  f32x4 xd[16];
#pragma unroll
  for (int ks = 0; ks < 8; ++ks) {
    xd[2 * ks]     = __builtin_nontemporal_load(
        reinterpret_cast<const f32x4*>(xp + ks * 32));
    xd[2 * ks + 1] = __builtin_nontemporal_load(
        reinterpret_cast<const f32x4*>(xp + ks * 32 + 4));
  }

  f32x4 acc[4] = {f32x4{0.f,0.f,0.f,0.f}, f32x4{0.f,0.f,0.f,0.f},
                  f32x4{0.f,0.f,0.f,0.f}, f32x4{0.f,0.f,0.f,0.f}};

#pragma unroll
  for (int ks = 0; ks < 8; ++ks) {
    const f32x4 xa = xd[2 * ks];
    const f32x4 xb = xd[2 * ks + 1];
    bf16x8 a;
    a[0] = (short)f2bf(xa[0]); a[1] = (short)f2bf(xa[1]);
    a[2] = (short)f2bf(xa[2]); a[3] = (short)f2bf(xa[3]);
    a[4] = (short)f2bf(xb[0]); a[5] = (short)f2bf(xb[1]);
    a[6] = (short)f2bf(xb[2]); a[7] = (short)f2bf(xb[3]);
#pragma unroll
    for (int nb = 0; nb < 4; ++nb) {
      const bf16x8 bfrag =
          *reinterpret_cast<const bf16x8*>(wp + nb * 16 * D_IN + ks * 32);
      acc[nb] = __builtin_amdgcn_mfma_f32_16x16x32_bf16(a, bfrag, acc[nb], 0, 0, 0);
    }
  }

#pragma unroll
  for (int nb = 0; nb < 4; ++nb) {
    const int col = nb * 16 + r16;
    const float bv = bias[col];
#pragma unroll
    for (int i = 0; i < 4; ++i) {
      const int row = m0 + kg * 4 + i;          // C/D: row=(lane>>4)*4+reg
      if (row < N_NODES)
        support[(size_t)row * D_OUT + col] = f2bf(acc[nb][i] + bv);
    }
  }
}

// ---------------------------------------------------------------------------
// Aggregation + LeakyReLU, 4 edges per gather instruction.
// One wave per node. Lane = (edge-group eg=lane>>4, col-group cl=lane&15).
// One gather inst fetches 4 edges' full 128B rows (u16x4 = 8B/lane);
// 16 edges in flight per wave. Tail branchless. shfl_xor(16,32) reduce,
// 16 lanes store one f32x4. NT on edge streams and out.
// ---------------------------------------------------------------------------
__global__ __launch_bounds__(256, 8) void agg_kernel(
    const ushort* __restrict__ support, const int* __restrict__ edge_src,
    const float* __restrict__ edge_val, const int* __restrict__ row_ptr,
    float* __restrict__ out) {
  const int wid = (blockIdx.x * 256 + threadIdx.x) >> 6;
  const int lane = threadIdx.x & 63;
  if (wid >= N_NODES) return;
  const int lo = row_ptr[wid];       // wave-uniform -> s_load
  const int hi = row_ptr[wid + 1];
  const int eg = lane >> 4;          // edge group 0..3
  const int cl = lane & 15;          // columns 4*cl .. 4*cl+3

  f32x4 acc0 = {0.f, 0.f, 0.f, 0.f};
  f32x4 acc1 = {0.f, 0.f, 0.f, 0.f};

  for (int e = lo; e < hi; e += 16) {
    int   s[4];
    float v[4];
#pragma unroll
    for (int q = 0; q < 4; ++q) {
      const int idx = e + q * 4 + eg;
      const int ic = idx < hi ? idx : hi - 1;           // clamped (hi>lo here)
      s[q] = __builtin_nontemporal_load(edge_src + ic);
      const float vv = __builtin_nontemporal_load(edge_val + ic);
      v[q] = idx < hi ? vv : 0.f;
    }
#pragma unroll
    for (int q = 0; q < 4; ++q) {
      const u16x4 g = *reinterpret_cast<const u16x4*>(
          support + (size_t)s[q] * D_OUT + cl * 4);
      f32x4& acc = (q & 1) ? acc1 : acc0;
      acc[0] = fmaf(v[q], bf2f(g[0]), acc[0]);
      acc[1] = fmaf(v[q], bf2f(g[1]), acc[1]);
      acc[2] = fmaf(v[q], bf2f(g[2]), acc[2]);
      acc[3] = fmaf(v[q], bf2f(g[3]), acc[3]);
    }
  }

  float r[4] = {acc0[0] + acc1[0], acc0[1] + acc1[1],
                acc0[2] + acc1[2], acc0[3] + acc1[3]};
#pragma unroll
  for (int c = 0; c < 4; ++c) {
    r[c] += __shfl_xor(r[c], 16, 64);   // combine edge groups 0<->1, 2<->3
    r[c] += __shfl_xor(r[c], 32, 64);   // combine {0,1}<->{2,3}
    r[c] = r[c] >= 0.f ? r[c] : NEG_SLOPE * r[c];
  }
  if (eg == 0) {
    f32x4 o = {r[0], r[1], r[2], r[3]};
    __builtin_nontemporal_store(
        o, reinterpret_cast<f32x4*>(out + (size_t)wid * D_OUT + cl * 4));
  }
}

// ---------------------------------------------------------------------------
extern "C" void kernel_launch(void* const* d_in, const int* in_sizes, int n_in,
                              void* d_out, int out_size, void* d_ws, size_t ws_size,
                              hipStream_t stream) {
  const float* x        = (const float*)d_in[0];
  const float* W        = (const float*)d_in[1];
  const float* b        = (const float*)d_in[2];
  const int*   edge_src = (const int*)d_in[3];
  const int*   edge_dst = (const int*)d_in[4];
  const float* edge_val = (const float*)d_in[5];
  float* out = (float*)d_out;

  // workspace layout
  ushort* support = (ushort*)d_ws;                                  // 6.4 MB
  char* p = (char*)d_ws + (size_t)N_NODES * D_OUT * sizeof(ushort);
  int* row_ptr = (int*)p;                                           // 200 KB
  p += (size_t)(N_NODES + 1) * sizeof(int);
  p = (char*)(((uintptr_t)p + 15) & ~(uintptr_t)15);
  ushort* Wb = (ushort*)p;                                          // 32 KB

  hipLaunchKernelGGL(prep_kernel, dim3((N_EDGES + 255) / 256), dim3(256), 0,
                     stream, W, Wb, edge_dst, row_ptr);
  hipLaunchKernelGGL(gemm_mfma, dim3((N_NODES + 63) / 64), dim3(256), 0,
                     stream, x, Wb, b, support);
  hipLaunchKernelGGL(agg_kernel, dim3((N_NODES * 64 + 255) / 256), dim3(256), 0,
                     stream, support, edge_src, edge_val, row_ptr, out);
}